// Round 8
// baseline (38.859 us; speedup 1.0000x reference)
//
#include <hip/hip_runtime.h>
#include <math.h>

#define NB 8
#define NH 256
#define NW 256
#define NHW (NH*NW)
#define NTOT (NB*NHW)
#define K2B (NB*NH)            // 2048 k2 blocks, one row each (max TLP - R4-proven)
#define NSLOT 32               // atomic spread slots per component
#define NCTR 32                // first-level completion counters (64 blocks each)

// ---------------------------------------------------------------------------
// K1: full vertical EDT, both masks, registers only, packed u8-pair output.
// EXACT R4 structure (best measured): 8 images x 16 col-groups = 128 blocks,
// thread (jl=t&15, c=t>>4) owns rows [c*16,c*16+16) of column grp*16+jl.
// Distances clamped to 255 (exact unless a whole 256-px column is single-
// valued, P~2^-255; verified absmax 0.0 in R6/R7). Block 0 zeroes the K2
// accumulators + counters (plain stores; dispatch-boundary coherence
// proven R4-R7).
// ---------------------------------------------------------------------------
__global__ __launch_bounds__(256) void k1_edt_cols(const float* __restrict__ tgt,
                                                   unsigned short* __restrict__ pk,
                                                   int* __restrict__ cnts,
                                                   float* __restrict__ acc,
                                                   int* __restrict__ ctr) {
    if (blockIdx.x == 0) {
        if (threadIdx.x < 5 * NSLOT) acc[threadIdx.x] = 0.0f;
        if (threadIdx.x < NCTR + 1) ctr[threadIdx.x] = 0;
    }

    const int blk = blockIdx.x;
    const int b = blk >> 4;
    const int grp = blk & 15;
    const int jl = threadIdx.x & 15;
    const int c = threadIdx.x >> 4;        // chunk 0..15
    const int col = grp * 16 + jl;
    const int r0 = c * 16;
    const float* t = tgt + b * NHW + col;
    unsigned short* po = pk + b * NHW + col;

    // ---- load 16 rows -> 16-bit mask ----
    unsigned int bits = 0;
#pragma unroll
    for (int r = 0; r < 16; ++r)
        bits |= ((t[(r0 + r) * NW] > 0.5f) ? 1u : 0u) << r;
    const unsigned int nbm = bits ^ 0xFFFFu;

    // ---- chunk summaries (global row of first/last true, sentinels) ----
    __shared__ int sTop[2][16][16];
    __shared__ int sBot[2][16][16];
    sTop[0][c][jl] = bits ? (r0 + __builtin_ctz(bits))      :  100000;
    sBot[0][c][jl] = bits ? (r0 + 31 - __builtin_clz(bits)) : -100000;
    sTop[1][c][jl] = nbm  ? (r0 + __builtin_ctz(nbm))       :  100000;
    sBot[1][c][jl] = nbm  ? (r0 + 31 - __builtin_clz(nbm))  : -100000;
    __syncthreads();

    // ---- per-block pos count ----
    __shared__ int sc[4];
    {
        int v = __popc(bits);
        for (int o = 32; o > 0; o >>= 1) v += __shfl_down(v, o, 64);
        if ((threadIdx.x & 63) == 0) sc[threadIdx.x >> 6] = v;
    }

    // ---- cross-chunk carries ----
    int laP = -100000, laN = -100000;
    for (int cc = 0; cc < c; ++cc) {
        laP = max(laP, sBot[0][cc][jl]);
        laN = max(laN, sBot[1][cc][jl]);
    }
    int fbP = 100000, fbN = 100000;
    for (int cc = c + 1; cc < 16; ++cc) {
        fbP = min(fbP, sTop[0][cc][jl]);
        fbN = min(fbN, sTop[1][cc][jl]);
    }
    __syncthreads();
    if (threadIdx.x == 0) cnts[blk] = sc[0] + sc[1] + sc[2] + sc[3];

    // ---- fwd scan (registers), bwd scan + combine + packed u8-pair store ----
    int fP[16], fN[16];
    int cp = (r0 - 1) - laP;
    int cn = (r0 - 1) - laN;
#pragma unroll
    for (int r = 0; r < 16; ++r) {
        cp = ((bits >> r) & 1u) ? 0 : cp + 1;
        cn = ((nbm  >> r) & 1u) ? 0 : cn + 1;
        fP[r] = cp; fN[r] = cn;
    }
    int bp = fbP - (r0 + 16);
    int bn = fbN - (r0 + 16);
#pragma unroll
    for (int r = 15; r >= 0; --r) {
        bp = ((bits >> r) & 1u) ? 0 : bp + 1;
        bn = ((nbm  >> r) & 1u) ? 0 : bn + 1;
        int gp = min(min(fP[r], bp), 255);
        int gn = min(min(fN[r], bn), 255);
        po[(r0 + r) * NW] = (unsigned short)(gp | (gn << 8));
    }
}

// ---------------------------------------------------------------------------
// K2: horizontal EDT (early-exit outward search) + fused loss, ONE ROW per
// block (2048 blocks = 8/CU -> max TLP, R4-proven fastest shape). Partials
// fold into 5 x 32 spread slots via device-scope atomicAdd (coherent point,
// NO fences - R6-proven). Completion via 2-level counter tree (32+1, 64 adds
// per address). Elected last block re-reads the slots with agent-scope
// atomic loads and finalizes the scalar loss.
// ---------------------------------------------------------------------------
__global__ __launch_bounds__(256) void k2_row_loss(const float* __restrict__ logits,
                                                   const unsigned short* __restrict__ pk,
                                                   const int* __restrict__ cnts,
                                                   int* __restrict__ ctr,
                                                   float* __restrict__ acc,
                                                   float* __restrict__ out) {
    const int bi = blockIdx.x;          // b*NH + row
    const int j = threadIdx.x;
    const int base = bi * NW;
    const int b = bi >> 8;

    __shared__ float sp[NW];
    __shared__ float sn[NW + 8];
    __shared__ float red[5][4];
    __shared__ float red2[5];
    __shared__ int lastFlag;

    const unsigned int pv = pk[base + j];
    const float dp = (float)(pv & 0xFFu);
    const float dn = (float)(pv >> 8);
    sp[j] = dp * dp;
    sn[j] = dn * dn;
    const bool m = (pv & 0xFFu) == 0u;     // pos pixel iff vertical pos-dist 0
    const float x = logits[base + j];
    __syncthreads();

    const float* sel = m ? sn : sp;
    float best = sel[j];
#pragma unroll
    for (int d = 1; d <= 8; ++d) {
        const float dd = (float)(d * d);
        int kl = j - d; kl = kl < 0 ? 0 : kl;
        int kr = j + d; kr = kr > NW - 1 ? NW - 1 : kr;
        best = fminf(best, sel[kl] + dd);
        best = fminf(best, sel[kr] + dd);
    }
    for (int d = 9; d < NW; ++d) {
        const float dd = (float)d * (float)d;
        if (dd >= best) break;
        int kl = j - d; kl = kl < 0 ? 0 : kl;
        int kr = j + d; kr = kr > NW - 1 ? NW - 1 : kr;
        best = fminf(best, sel[kl] + dd);
        best = fminf(best, sel[kr] + dd);
    }

    const float tv = m ? 1.0f : 0.0f;
    float res = m ? (1.0f - sqrtf(best)) : sqrtf(best);
    const float sig = 1.0f / (1.0f + expf(-x));
    const float splus = (x > 0.0f) ? (x + log1pf(expf(-x))) : log1pf(expf(x));

    // has_pos gate for this image (uniform scalar loads, L2-hit)
    {
        int s = 0;
#pragma unroll
        for (int g = 0; g < 16; ++g) s += cnts[b * 16 + g];
        if (s == 0) res = 0.0f;
    }

    float v0 = sig;
    float v1 = tv;
    float v2 = m ? sig : 0.0f;
    float v3 = splus - x * tv;
    float v4 = sig * res;

    const int lane = j & 63, wid = j >> 6;
    for (int o = 32; o > 0; o >>= 1) {
        v0 += __shfl_down(v0, o, 64);
        v1 += __shfl_down(v1, o, 64);
        v2 += __shfl_down(v2, o, 64);
        v3 += __shfl_down(v3, o, 64);
        v4 += __shfl_down(v4, o, 64);
    }
    if (lane == 0) {
        red[0][wid] = v0; red[1][wid] = v1; red[2][wid] = v2;
        red[3][wid] = v3; red[4][wid] = v4;
    }
    __syncthreads();
    if (j < 5) {
        float p = red[j][0] + red[j][1] + red[j][2] + red[j][3];
        atomicAdd(&acc[j * NSLOT + (bi & (NSLOT - 1))], p);    // coherent point
    }
    if (j == 0) {
        // order this wave's data atomics before the completion counts
        asm volatile("s_waitcnt vmcnt(0)" ::: "memory");
        int flag = 0;
        int c1 = atomicAdd(&ctr[bi & (NCTR - 1)], 1);          // level 1
        if (c1 == K2B / NCTR - 1) {
            int s = atomicAdd(&ctr[NCTR], 1);                  // level 2
            flag = (s == NCTR - 1) ? 1 : 0;
        }
        lastFlag = flag;
    }
    __syncthreads();
    if (!lastFlag) return;

    // ---- elected last block: read accumulators (coherent) + finalize ----
    if (j < 5 * NSLOT) {
        float v = __hip_atomic_load(&acc[j], __ATOMIC_RELAXED, __HIP_MEMORY_SCOPE_AGENT);
        for (int o = 16; o > 0; o >>= 1) v += __shfl_down(v, o, 32);
        if ((j & 31) == 0) red2[j >> 5] = v;
    }
    __syncthreads();
    if (j == 0) {
        float ssig  = red2[0];
        float st    = red2[1];
        float inter = red2[2];
        float sbce  = red2[3];
        float sbdy  = red2[4];
        const float SMOOTH = 1e-5f;
        float dice = 1.0f - (2.0f * inter + SMOOTH) / (ssig + st + SMOOTH);
        float n = (float)NTOT;
        out[0] = 0.5f * dice + 0.5f * (sbce / n) + 0.5f * (sbdy / n);
    }
}

extern "C" void kernel_launch(void* const* d_in, const int* in_sizes, int n_in,
                              void* d_out, int out_size, void* d_ws, size_t ws_size,
                              hipStream_t stream) {
    const float* logits = (const float*)d_in[0];
    const float* tgt    = (const float*)d_in[1];
    float* out = (float*)d_out;

    unsigned short* pk = (unsigned short*)d_ws;        // NTOT u16 (packed dp,dn u8)
    float* acc = (float*)((char*)d_ws + NTOT * 2);     // 5*NSLOT f32
    int*   cnts = (int*)(acc + 5 * NSLOT);             // 128 ints
    int*   ctr  = cnts + 128;                          // NCTR+1 ints

    k1_edt_cols<<<NB * 16, 256, 0, stream>>>(tgt, pk, cnts, acc, ctr);
    k2_row_loss<<<K2B, 256, 0, stream>>>(logits, pk, cnts, ctr, acc, out);
}

// Round 9
// 18.065 us; speedup vs baseline: 2.1510x; 2.1510x over previous
//
#include <hip/hip_runtime.h>
#include <math.h>

#define NB 8
#define NH 256
#define NW 256
#define NHW (NH*NW)
#define NTOT (NB*NHW)
#define K2B (NB*NH)            // 2048 k2 blocks, one row each (R4-proven best shape)
#define NSLOT 32               // data-atomic slots per component
#define NCTR 32                // level-1 completion counters
#define PAD 64                 // ints/floats per atomic slot = 256B -> one L2 line each
#define CLAMPI 1023

// ---------------------------------------------------------------------------
// K1: EXACT R4 kernel (best measured): full vertical EDT, both masks,
// register scans, packed u16-pair u32 output. 8 images x 16 col-groups =
// 128 blocks x 256 threads; thread (jl=t&15, c=t>>4) owns rows
// [c*16, c*16+16) of column grp*16+jl. Block 0 additionally zeroes the
// PADDED accumulator/counter lines (plain stores; dispatch-boundary
// coherence proven R4-R8).
// ---------------------------------------------------------------------------
__global__ __launch_bounds__(256) void k1_edt_cols(const float* __restrict__ tgt,
                                                   unsigned int* __restrict__ pk,
                                                   int* __restrict__ cnts,
                                                   float* __restrict__ acc,
                                                   int* __restrict__ ctr) {
    if (blockIdx.x == 0) {
        if (threadIdx.x < 5 * NSLOT) acc[threadIdx.x * PAD] = 0.0f;
        if (threadIdx.x < NCTR + 1) ctr[threadIdx.x * PAD] = 0;
    }

    const int blk = blockIdx.x;
    const int b = blk >> 4;
    const int grp = blk & 15;
    const int jl = threadIdx.x & 15;
    const int c = threadIdx.x >> 4;        // chunk 0..15
    const int col = grp * 16 + jl;
    const int r0 = c * 16;
    const float* t = tgt + b * NHW + col;
    unsigned int* po = pk + b * NHW + col;

    // ---- load 16 rows -> 16-bit mask ----
    unsigned int bits = 0;
#pragma unroll
    for (int r = 0; r < 16; ++r)
        bits |= ((t[(r0 + r) * NW] > 0.5f) ? 1u : 0u) << r;
    const unsigned int nbm = bits ^ 0xFFFFu;

    // ---- chunk summaries (global row of first/last true, sentinels) ----
    __shared__ int sTop[2][16][16];
    __shared__ int sBot[2][16][16];
    sTop[0][c][jl] = bits ? (r0 + __builtin_ctz(bits))      :  100000;
    sBot[0][c][jl] = bits ? (r0 + 31 - __builtin_clz(bits)) : -100000;
    sTop[1][c][jl] = nbm  ? (r0 + __builtin_ctz(nbm))       :  100000;
    sBot[1][c][jl] = nbm  ? (r0 + 31 - __builtin_clz(nbm))  : -100000;
    __syncthreads();

    // ---- per-block pos count ----
    __shared__ int sc[4];
    {
        int v = __popc(bits);
        for (int o = 32; o > 0; o >>= 1) v += __shfl_down(v, o, 64);
        if ((threadIdx.x & 63) == 0) sc[threadIdx.x >> 6] = v;
    }

    // ---- cross-chunk carries ----
    int laP = -100000, laN = -100000;
    for (int cc = 0; cc < c; ++cc) {
        laP = max(laP, sBot[0][cc][jl]);
        laN = max(laN, sBot[1][cc][jl]);
    }
    int fbP = 100000, fbN = 100000;
    for (int cc = c + 1; cc < 16; ++cc) {
        fbP = min(fbP, sTop[0][cc][jl]);
        fbN = min(fbN, sTop[1][cc][jl]);
    }
    __syncthreads();
    if (threadIdx.x == 0) cnts[blk] = sc[0] + sc[1] + sc[2] + sc[3];

    // ---- fwd scan (registers), bwd scan + combine + packed store ----
    int fP[16], fN[16];
    int cp = (r0 - 1) - laP;
    int cn = (r0 - 1) - laN;
#pragma unroll
    for (int r = 0; r < 16; ++r) {
        cp = ((bits >> r) & 1u) ? 0 : cp + 1;
        cn = ((nbm  >> r) & 1u) ? 0 : cn + 1;
        fP[r] = cp; fN[r] = cn;
    }
    int bp = fbP - (r0 + 16);
    int bn = fbN - (r0 + 16);
#pragma unroll
    for (int r = 15; r >= 0; --r) {
        bp = ((bits >> r) & 1u) ? 0 : bp + 1;
        bn = ((nbm  >> r) & 1u) ? 0 : bn + 1;
        int gp = min(min(fP[r], bp), CLAMPI);
        int gn = min(min(fN[r], bn), CLAMPI);
        po[(r0 + r) * NW] = (unsigned int)gp | ((unsigned int)gn << 16);
    }
}

// ---------------------------------------------------------------------------
// K2: EXACT R4 body (one row per block, 2048 blocks, early-exit outward
// search, fused loss partials) + fence-free fused finalize. Handoff atomics
// are PADDED one-per-256B-line: 160 data lines (64 adds each), 32+1 counter
// lines (64 adds each) — per-line serialization (~13ns/op, R1/R8-calibrated)
// now overlaps across L2 channels instead of stacking on ~11 lines.
// ---------------------------------------------------------------------------
__global__ __launch_bounds__(256) void k2_row_loss(const float* __restrict__ logits,
                                                   const unsigned int* __restrict__ pk,
                                                   const int* __restrict__ cnts,
                                                   int* __restrict__ ctr,
                                                   float* __restrict__ acc,
                                                   float* __restrict__ out) {
    const int bi = blockIdx.x;          // b*NH + row
    const int j = threadIdx.x;
    const int base = bi * NW;
    const int b = bi >> 8;

    __shared__ float sp[NW];
    __shared__ float sn[NW + 8];
    __shared__ float red[5][4];
    __shared__ float red2[5];
    __shared__ int lastFlag;

    const unsigned int pv = pk[base + j];
    const float dp = (float)(pv & 0xFFFFu);
    const float dn = (float)(pv >> 16);
    sp[j] = dp * dp;
    sn[j] = dn * dn;
    const bool m = (pv & 0xFFFFu) == 0u;   // pos pixel iff vertical pos-dist 0
    const float x = logits[base + j];
    __syncthreads();

    const float* sel = m ? sn : sp;
    float best = sel[j];
#pragma unroll
    for (int d = 1; d <= 8; ++d) {
        const float dd = (float)(d * d);
        int kl = j - d; kl = kl < 0 ? 0 : kl;
        int kr = j + d; kr = kr > NW - 1 ? NW - 1 : kr;
        best = fminf(best, sel[kl] + dd);
        best = fminf(best, sel[kr] + dd);
    }
    for (int d = 9; d < NW; ++d) {
        const float dd = (float)d * (float)d;
        if (dd >= best) break;
        int kl = j - d; kl = kl < 0 ? 0 : kl;
        int kr = j + d; kr = kr > NW - 1 ? NW - 1 : kr;
        best = fminf(best, sel[kl] + dd);
        best = fminf(best, sel[kr] + dd);
    }

    const float tv = m ? 1.0f : 0.0f;
    float res = m ? (1.0f - sqrtf(best)) : sqrtf(best);
    const float sig = 1.0f / (1.0f + expf(-x));
    const float splus = (x > 0.0f) ? (x + log1pf(expf(-x))) : log1pf(expf(x));

    // has_pos gate for this image (uniform scalar loads, L2-hit)
    {
        int s = 0;
#pragma unroll
        for (int g = 0; g < 16; ++g) s += cnts[b * 16 + g];
        if (s == 0) res = 0.0f;
    }

    float v0 = sig;
    float v1 = tv;
    float v2 = m ? sig : 0.0f;
    float v3 = splus - x * tv;
    float v4 = sig * res;

    const int lane = j & 63, wid = j >> 6;
    for (int o = 32; o > 0; o >>= 1) {
        v0 += __shfl_down(v0, o, 64);
        v1 += __shfl_down(v1, o, 64);
        v2 += __shfl_down(v2, o, 64);
        v3 += __shfl_down(v3, o, 64);
        v4 += __shfl_down(v4, o, 64);
    }
    if (lane == 0) {
        red[0][wid] = v0; red[1][wid] = v1; red[2][wid] = v2;
        red[3][wid] = v3; red[4][wid] = v4;
    }
    __syncthreads();
    if (j < 5) {
        float p = red[j][0] + red[j][1] + red[j][2] + red[j][3];
        // one padded line per (component, slot): 64 adds per line
        atomicAdd(&acc[(j * NSLOT + (bi & (NSLOT - 1))) * PAD], p);
    }
    if (j == 0) {
        // order this wave's data atomics before the completion counts
        asm volatile("s_waitcnt vmcnt(0)" ::: "memory");
        int flag = 0;
        int c1 = atomicAdd(&ctr[(bi & (NCTR - 1)) * PAD], 1);  // level 1, padded
        if (c1 == K2B / NCTR - 1) {
            int s = atomicAdd(&ctr[NCTR * PAD], 1);            // level 2
            flag = (s == NCTR - 1) ? 1 : 0;
        }
        lastFlag = flag;
    }
    __syncthreads();
    if (!lastFlag) return;

    // ---- elected last block: read padded slots (coherent) + finalize ----
    if (j < 5 * NSLOT) {
        float v = __hip_atomic_load(&acc[j * PAD], __ATOMIC_RELAXED,
                                    __HIP_MEMORY_SCOPE_AGENT);
        for (int o = 16; o > 0; o >>= 1) v += __shfl_down(v, o, 32);
        if ((j & 31) == 0) red2[j >> 5] = v;
    }
    __syncthreads();
    if (j == 0) {
        float ssig  = red2[0];
        float st    = red2[1];
        float inter = red2[2];
        float sbce  = red2[3];
        float sbdy  = red2[4];
        const float SMOOTH = 1e-5f;
        float dice = 1.0f - (2.0f * inter + SMOOTH) / (ssig + st + SMOOTH);
        float n = (float)NTOT;
        out[0] = 0.5f * dice + 0.5f * (sbce / n) + 0.5f * (sbdy / n);
    }
}

extern "C" void kernel_launch(void* const* d_in, const int* in_sizes, int n_in,
                              void* d_out, int out_size, void* d_ws, size_t ws_size,
                              hipStream_t stream) {
    const float* logits = (const float*)d_in[0];
    const float* tgt    = (const float*)d_in[1];
    float* out = (float*)d_out;

    unsigned int* pk = (unsigned int*)d_ws;            // NTOT u32 (packed u16 pair)
    float* acc = (float*)d_ws + NTOT;                  // 160 slots x 256B padded
    int*   ctr = (int*)(acc + 5 * NSLOT * PAD);        // 33 slots x 256B padded
    int*   cnts = ctr + (NCTR + 1) * PAD;              // 128 ints

    k1_edt_cols<<<NB * 16, 256, 0, stream>>>(tgt, pk, cnts, acc, ctr);
    k2_row_loss<<<K2B, 256, 0, stream>>>(logits, pk, cnts, ctr, acc, out);
}